// Round 3
// baseline (300.588 us; speedup 1.0000x reference)
//
#include <hip/hip_runtime.h>
#include <math.h>

#define NN 512
#define WD 64
#define RH 4
#define OUTD 256
#define IND 256
#define IFACE_ 471
#define CDIM_ 727
#define TC 2181   // 3*CDIM
#define BS_ 64

// ---- output offsets (floats) ----
#define O_Y   0
#define O_MN  16384
#define O_UN  2113536
#define O_LN  2146304
#define O_WPN 18923520
#define O_WRN 18956288
#define O_WW  19087360
#define O_HC  19120128

// ---- workspace offsets (floats) ----
// P1: 16 slices x (128x2181) GRU partials.  P2: 12 slices x (128x512) iface partials.
// FWD/BWD/SIM alias P1 (dead after k_gru; k_small zeroes FWD/BWD after that).
#define P1_STRIDE 279168     // 128*2181
#define WS_P1   0            // 16*279168 = 4466688
#define WS_FWD  0            // 131072 (aliases P1)
#define WS_BWD  131072       // 131072 (aliases P1)
#define WS_SIM  262144       // 131072 (aliases P1)
#define WS_P2   4466688      // 12*65536 = 786432
#define P2_STRIDE 65536      // 128*512
#define WS_C    5253120      // 128*727 = 93056
#define WS_PAR  5346176      // 64*512 = 32768  -> end 5378944 floats (21.5 MB)

// ---- per-batch param layout (stride 512) ----
#define PK_NKW 0
#define PK_ER  64
#define PK_WV  128
#define PK_NKR 192
#define PK_BR  448
#define PK_MOD 452
#define PK_BW  464
#define PK_AG  465
#define PK_WG  466
#define PK_FG  468

__device__ __forceinline__ float sigf(float x){ return 1.f/(1.f+expf(-x)); }
__device__ __forceinline__ float softplusf(float x){ return (x>20.f)? x : log1pf(expf(x)); }
__device__ __forceinline__ float geluf(float x){ return 0.5f*x*(1.f+erff(x*0.70710678118654752440f)); }
__device__ __forceinline__ float dot4(float4 a, float4 b){ return a.x*b.x+a.y*b.y+a.z*b.z+a.w*b.w; }
__device__ __forceinline__ void fma4(float4& a, float s, float4 v){ a.x+=s*v.x; a.y+=s*v.y; a.z+=s*v.z; a.w+=s*v.w; }
__device__ __forceinline__ float4 ln_combine(float4 l4, float4 wwj, float4 wpj, float base, float wwi){
  float4 r;
  r.x = (base - wwj.x)*l4.x + wwi*wpj.x;
  r.y = (base - wwj.y)*l4.y + wwi*wpj.y;
  r.z = (base - wwj.z)*l4.z + wwi*wpj.z;
  r.w = (base - wwj.w)*l4.w + wwi*wpj.w;
  return r;
}
__device__ __forceinline__ void diag_zero(float4& r, int d){
  if (d==0) r.x=0.f; else if (d==1) r.y=0.f; else if (d==2) r.z=0.f; else if (d==3) r.w=0.f;
}

// ======================= broadcast GEMM: 128 rows x 64 cols x K-slice =======================
// As staged once (no K-chunk barriers); A read via wave-broadcast b128; B streamed from global.
__device__ __forceinline__ void gemm_bc_body(
    const float* __restrict__ A, int lda, int K,
    const float* __restrict__ B, int ldb, int Ncols,
    float* __restrict__ C, int ldc,
    int k0, int klen, int n0, int t, float* As)
{
  // stage A-slice: As[m][kk] (m 0..127, kk 0..63), zero-padded beyond klen
  for (int i = t; i < 8192; i += 256) {
    int m = i >> 6, kk = i & 63;
    As[i] = (kk < klen) ? A[m*lda + k0 + kk] : 0.f;
  }
  int c = n0 + (t & 63);
  int cc = (c < Ncols) ? c : 0;
  int m0 = (t >> 6) * 32;
  float acc[32];
  #pragma unroll
  for (int r = 0; r < 32; r++) acc[r] = 0.f;
  __syncthreads();
  const float* Bc = B + cc;
  for (int kk = 0; kk < 64; kk += 4) {
    int r0 = k0 + kk;
    int i0 = min(r0+0, K-1), i1 = min(r0+1, K-1), i2 = min(r0+2, K-1), i3 = min(r0+3, K-1);
    float b0 = Bc[(size_t)i0*ldb];
    float b1 = Bc[(size_t)i1*ldb];
    float b2 = Bc[(size_t)i2*ldb];
    float b3 = Bc[(size_t)i3*ldb];
    const float* ap = As + kk;
    #pragma unroll
    for (int r = 0; r < 32; r++) {
      float4 a4 = *(const float4*)&ap[(m0+r)*64];
      acc[r] += a4.x*b0 + a4.y*b1 + a4.z*b2 + a4.w*b3;
    }
  }
  if (c < Ncols) {
    float* Cp = C + c;
    #pragma unroll
    for (int r = 0; r < 32; r++) Cp[(size_t)(m0+r)*ldc] = acc[r];
  }
}

// grid (35, 16): x = n-tile of 64 over 2181 cols, y = K-slice (0-3: x-GEMM, 4-15: h-GEMM)
__global__ __launch_bounds__(256) void k_gemm1(const float* __restrict__ xin,
    const float* __restrict__ hin, const float* __restrict__ gk,
    const float* __restrict__ grk, float* __restrict__ P)
{
  __shared__ float As[8192];
  int s = blockIdx.y;
  int n0 = blockIdx.x * 64;
  const float* A; const float* B; int lda, K, k0, klen;
  if (s < 4) { A = xin; lda = IND;  B = gk;  K = IND;  k0 = s*64;      klen = 64; }
  else       { A = hin; lda = CDIM_; B = grk; K = CDIM_; k0 = (s-4)*61; klen = (s==15)?56:61; }
  gemm_bc_body(A, lda, K, B, TC, TC, P + (size_t)s*P1_STRIDE, TC,
               k0, klen, n0, threadIdx.x, As);
}

// grid (8, 12): iface partials, 512-wide padded rows
__global__ __launch_bounds__(256) void k_gemm2(const float* __restrict__ cbuf,
    const float* __restrict__ Wif, float* __restrict__ P2)
{
  __shared__ float As[8192];
  int s = blockIdx.y;
  int k0 = s*61, klen = (s==11)?56:61;
  gemm_bc_body(cbuf, CDIM_, CDIM_, Wif, IFACE_, IFACE_,
               P2 + (size_t)s*P2_STRIDE, 512,
               k0, klen, blockIdx.x*64, threadIdx.x, As);
}

// ======================= GRU pointwise (sums 16 slices; h-gate split by slice range) ==========
__global__ __launch_bounds__(256) void k_gru(const float* __restrict__ P,
    const float* __restrict__ hprev, const float* __restrict__ gbias,
    float* __restrict__ cbuf, float* __restrict__ out_hc)
{
  int idx = blockIdx.x*256 + threadIdx.x;
  if (idx >= 128*CDIM_) return;
  int p = idx / CDIM_, u = idx % CDIM_;
  float zs=0.f, rs=0.f, xh=0.f, rh=0.f;
  #pragma unroll
  for (int s = 0; s < 16; s++) {
    const float* Ps = P + (size_t)s*P1_STRIDE + (size_t)p*TC;
    zs += Ps[u]; rs += Ps[CDIM_+u];
    float hv = Ps[2*CDIM_+u];
    if (s < 4) xh += hv; else rh += hv;
  }
  zs += gbias[u] + gbias[TC+u];
  rs += gbias[CDIM_+u] + gbias[TC+CDIM_+u];
  xh += gbias[2*CDIM_+u];
  rh += gbias[TC+2*CDIM_+u];
  float z_ = sigf(zs);
  float r_ = sigf(rs);
  float hh = geluf(xh + r_*rh);
  float h  = hprev[(size_t)p*CDIM_ + u];
  float cv = z_*h + (1.f - z_)*hh;
  cbuf[(size_t)p*CDIM_ + u] = cv;
  out_hc[(size_t)p*CDIM_ + u] = cv;
}

// ======================= per-batch small ops (+ zero fwd/bwd) =======================
__global__ __launch_bounds__(512) void k_small(
    const float* __restrict__ P2, const float* __restrict__ M,
    const float* __restrict__ usage, const float* __restrict__ W_read,
    const float* __restrict__ W_write, const float* __restrict__ Wp,
    float* __restrict__ out, float* __restrict__ params,
    float* __restrict__ zbuf)
{
  __shared__ float ifr[IFACE_], ifw[IFACE_];
  __shared__ float su[512]; __shared__ int si[512];
  __shared__ float alloc_l[512];
  __shared__ float s_nkw[64];
  __shared__ float s_fg[4];
  __shared__ float s_bw, s_ag, s_wg;
  __shared__ float wredA[8], wredB[8], warpTot[8];
  int b = blockIdx.x, t = threadIdx.x;
  int lane = t & 63, wid = t >> 6;
  float* pp = params + b*512;

  // 0. zero fwd+bwd accumulators (262144 floats total across 64 blocks)
  {
    float4 z4 = make_float4(0.f,0.f,0.f,0.f);
    float4* zp = (float4*)zbuf;
    int gid = b*512 + t;
    zp[gid] = z4;
    zp[gid + 32768] = z4;
  }

  // 1. reduce iface partials for both controller rows
  if (t < IFACE_) {
    float sr = 0.f, sw = 0.f;
    #pragma unroll
    for (int s = 0; s < 12; s++) {
      const float* base = P2 + (size_t)s*P2_STRIDE;
      sr += base[(b*2+0)*512 + t];
      sw += base[(b*2+1)*512 + t];
    }
    ifr[t] = sr; ifw[t] = sw;
  }
  __syncthreads();

  // 2. activations / params
  if (t < 64) {
    float ss = 0.f;
    for (int w = 0; w < 64; w++) { float v = ifw[260+w]; ss += v*v; }
    float rn = rsqrtf(fmaxf(ss, 1e-12f));
    float nk = ifw[260+t]*rn;
    pp[PK_NKW + t] = nk; s_nkw[t] = nk;
    pp[PK_ER  + t] = sigf(ifw[325+t]);
    pp[PK_WV  + t] = ifw[389+t];
  } else if (t < 320) {
    int r = (t-64) >> 6, w = (t-64) & 63;
    float ss = 0.f;
    for (int w2 = 0; w2 < 64; w2++) { float v = ifr[r*64+w2]; ss += v*v; }
    pp[PK_NKR + r*64 + w] = ifr[r*64+w]*rsqrtf(fmaxf(ss, 1e-12f));
  } else if (t < 324) {
    pp[PK_BR + (t-320)] = 1.f + softplusf(ifr[256 + (t-320)]);
  } else if (t < 336) {
    int i = t-324; int mm = i >> 2, r = i & 3;
    float v0 = ifr[459+r], v1 = ifr[459+4+r], v2 = ifr[459+8+r];
    float mx = fmaxf(v0, fmaxf(v1, v2));
    float e0 = expf(v0-mx), e1 = expf(v1-mx), e2 = expf(v2-mx);
    float den = e0+e1+e2;
    pp[PK_MOD + i] = (mm==0 ? e0 : (mm==1 ? e1 : e2)) / den;
  } else if (t == 336) { float v = 1.f + softplusf(ifw[324]); pp[PK_BW] = v; s_bw = v; }
  else if (t == 337) { float v = sigf(ifw[457]); pp[PK_AG] = v; s_ag = v; }
  else if (t == 338) { float v = sigf(ifw[458]); pp[PK_WG] = v; s_wg = v; }
  else if (t < 343) { int r = t-339; float v = sigf(ifw[453+r]); pp[PK_FG+r] = v; s_fg[r] = v; }
  __syncthreads();

  // 3. usage_n
  float un;
  {
    float4 wr4 = *(const float4*)&W_read[(size_t)(b*512+t)*4];
    float ret = (1.f - s_fg[0]*wr4.x)*(1.f - s_fg[1]*wr4.y)*(1.f - s_fg[2]*wr4.z)*(1.f - s_fg[3]*wr4.w);
    float u = usage[b*512+t], w = W_write[b*512+t];
    un = (u + w - u*w)*ret;
    out[O_UN + b*512 + t] = un;
  }

  // 4. hybrid bitonic sort ascending (value, index)
  float v = un; int key = t;
  for (int k = 2; k <= 512; k <<= 1) {
    for (int j = k >> 1; j > 0; j >>= 1) {
      bool dir = ((t & k) == 0);
      if (j >= 64) {
        su[t] = v; si[t] = key;
        __syncthreads();
        float pv = su[t ^ j]; int pi = si[t ^ j];
        bool gt = (v > pv) || (v == pv && key > pi);
        bool take = ((t & j) == 0) ? (gt == dir) : (gt != dir);
        if (take) { v = pv; key = pi; }
        __syncthreads();
      } else {
        float pv = __shfl_xor(v, j);
        int   pi = __shfl_xor(key, j);
        bool gt = (v > pv) || (v == pv && key > pi);
        bool take = ((t & j) == 0) ? (gt == dir) : (gt != dir);
        if (take) { v = pv; key = pi; }
      }
    }
  }

  // 5. cumprod scan -> exclusive -> W_alloc scatter
  {
    float x = v;
    #pragma unroll
    for (int off = 1; off < 64; off <<= 1) {
      float y = __shfl_up(x, off);
      if (lane >= off) x *= y;
    }
    if (lane == 63) warpTot[wid] = x;
    __syncthreads();
    float pre = 1.f;
    for (int w2 = 0; w2 < wid; w2++) pre *= warpTot[w2];
    float xm1 = __shfl_up(x, 1);
    float excl = (lane == 0) ? pre : pre*xm1;
    alloc_l[key] = (1.f - v)*excl;
  }
  __syncthreads();

  // 6. write content lookup softmax
  float mysim;
  {
    const float* mrow = M + (size_t)(b*512+t)*64;
    float ss = 0.f, dt = 0.f;
    #pragma unroll
    for (int i = 0; i < 16; i++) {
      float4 m4 = *(const float4*)&mrow[i*4];
      float4 k4 = *(const float4*)&s_nkw[i*4];
      ss += dot4(m4, m4); dt += dot4(m4, k4);
    }
    mysim = dt * rsqrtf(fmaxf(ss, 1e-12f)) * s_bw;
  }
  float mw = mysim;
  #pragma unroll
  for (int off = 32; off > 0; off >>= 1) mw = fmaxf(mw, __shfl_xor(mw, off));
  if (lane == 0) wredA[wid] = mw;
  __syncthreads();
  float mx = wredA[0];
  #pragma unroll
  for (int i = 1; i < 8; i++) mx = fmaxf(mx, wredA[i]);
  float e = expf(mysim - mx);
  float sw_ = e;
  #pragma unroll
  for (int off = 32; off > 0; off >>= 1) sw_ += __shfl_xor(sw_, off);
  if (lane == 0) wredB[wid] = sw_;
  __syncthreads();
  float den = 0.f;
  #pragma unroll
  for (int i = 0; i < 8; i++) den += wredB[i];
  float lkp = e / den;

  // 7. Ww + sum
  float ww = s_wg * (s_ag * alloc_l[t] + (1.f - s_ag) * lkp);
  out[O_WW + b*512 + t] = ww;
  float wsum = ww;
  #pragma unroll
  for (int off = 32; off > 0; off >>= 1) wsum += __shfl_xor(wsum, off);
  if (lane == 0) wredA[wid] = wsum;
  __syncthreads();
  float sum = 0.f;
  #pragma unroll
  for (int i = 0; i < 8; i++) sum += wredA[i];

  // 8. Wp_n (merged)
  out[O_WPN + b*512 + t] = (1.f - sum)*Wp[b*512+t] + ww;
}

// ======================= M_n elementwise + read-lookup sims =======================
__global__ __launch_bounds__(256) void k_mn(const float* __restrict__ M,
    const float* __restrict__ params, float* __restrict__ out,
    float* __restrict__ sims)
{
  int t = threadIdx.x;
  int idx = blockIdx.x*256 + t;
  int w4 = idx & 15, n = (idx >> 4) & 511, b = idx >> 13;
  float ww = out[O_WW + b*512 + n];
  const float* pp = params + b*512;
  float4 er = *(const float4*)&pp[PK_ER + w4*4];
  float4 wv = *(const float4*)&pp[PK_WV + w4*4];
  float4 m4 = *(const float4*)&M[(size_t)idx*4];
  float4 r;
  r.x = m4.x*(1.f - ww*er.x) + ww*wv.x;
  r.y = m4.y*(1.f - ww*er.y) + ww*wv.y;
  r.z = m4.z*(1.f - ww*er.z) + ww*wv.z;
  r.w = m4.w*(1.f - ww*er.w) + ww*wv.w;
  *(float4*)&out[O_MN + (size_t)idx*4] = r;
  float4 nk0 = *(const float4*)&pp[PK_NKR +       w4*4];
  float4 nk1 = *(const float4*)&pp[PK_NKR +  64 + w4*4];
  float4 nk2 = *(const float4*)&pp[PK_NKR + 128 + w4*4];
  float4 nk3 = *(const float4*)&pp[PK_NKR + 192 + w4*4];
  float ss = dot4(r, r);
  float d0 = dot4(r, nk0), d1 = dot4(r, nk1), d2 = dot4(r, nk2), d3 = dot4(r, nk3);
  #pragma unroll
  for (int m = 1; m < 16; m <<= 1) {
    ss += __shfl_xor(ss, m);
    d0 += __shfl_xor(d0, m); d1 += __shfl_xor(d1, m);
    d2 += __shfl_xor(d2, m); d3 += __shfl_xor(d3, m);
  }
  if ((t & 15) == 0) {
    float rn = rsqrtf(fmaxf(ss, 1e-12f));
    float4 s;
    s.x = d0*rn*pp[PK_BR+0]; s.y = d1*rn*pp[PK_BR+1];
    s.z = d2*rn*pp[PK_BR+2]; s.w = d3*rn*pp[PK_BR+3];
    *(float4*)&sims[(size_t)(b*512+n)*4] = s;
  }
}

// ======================= L_n + fused W_fwd / W_bwd (wave-per-row, j-split) ===================
// grid: 64 batches x 8 i-tiles x 2 j-halves = 1024 blocks
__global__ __launch_bounds__(256) void k_ln(const float* __restrict__ L,
    const float* __restrict__ Wp, const float* __restrict__ W_read,
    float* __restrict__ out, float* __restrict__ fwd, float* __restrict__ bwd)
{
  __shared__ float wwl[512], wpl[512];
  __shared__ float wrT[4][512];
  __shared__ float wbuf[4][1024];
  int bid = blockIdx.x;
  int b  = bid >> 4;
  int i0 = ((bid >> 1) & 7) * 64;
  int jh = bid & 1;
  int t = threadIdx.x, lane = t & 63, wid = t >> 6;
  for (int q = 0; q < 2; q++) {
    int n = t + q*256;
    wwl[n] = out[O_WW + b*512 + n];
    wpl[n] = Wp[b*512 + n];
    float4 w4 = *(const float4*)&W_read[(size_t)(b*512+n)*4];
    wrT[0][n] = w4.x; wrT[1][n] = w4.y; wrT[2][n] = w4.z; wrT[3][n] = w4.w;
  }
  __syncthreads();
  int jb = jh*256 + lane*4;
  float4 wwj = *(const float4*)&wwl[jb];
  float4 wpj = *(const float4*)&wpl[jb];
  float4 wrj[4], bacc[4];
  #pragma unroll
  for (int rr = 0; rr < 4; rr++) {
    wrj[rr] = *(const float4*)&wrT[rr][jb];
    bacc[rr] = make_float4(0.f,0.f,0.f,0.f);
  }
  const float* Lb  = L + (size_t)b*262144;
  float* LNb = out + O_LN + (size_t)b*262144;
  #pragma unroll 4
  for (int ri = 0; ri < 16; ri++) {
    int gi = i0 + ri*4 + wid;
    float wwi = wwl[gi], base = 1.f - wwi;
    float wi0 = wrT[0][gi], wi1 = wrT[1][gi], wi2 = wrT[2][gi], wi3 = wrT[3][gi];
    float4 l4 = *(const float4*)&Lb[(size_t)gi*512 + jb];
    float4 r4 = ln_combine(l4, wwj, wpj, base, wwi);
    diag_zero(r4, gi - jb);
    *(float4*)&LNb[(size_t)gi*512 + jb] = r4;
    float f0 = dot4(r4, wrj[0]);
    float f1 = dot4(r4, wrj[1]);
    float f2 = dot4(r4, wrj[2]);
    float f3 = dot4(r4, wrj[3]);
    fma4(bacc[0], wi0, r4); fma4(bacc[1], wi1, r4);
    fma4(bacc[2], wi2, r4); fma4(bacc[3], wi3, r4);
    #pragma unroll
    for (int off = 32; off > 0; off >>= 1) {
      f0 += __shfl_xor(f0, off);
      f1 += __shfl_xor(f1, off);
      f2 += __shfl_xor(f2, off);
      f3 += __shfl_xor(f3, off);
    }
    if (lane == 0) {
      float* fp = &fwd[(size_t)(b*512+gi)*4];
      atomicAdd(&fp[0], f0); atomicAdd(&fp[1], f1);
      atomicAdd(&fp[2], f2); atomicAdd(&fp[3], f3);
    }
  }
  #pragma unroll
  for (int rr = 0; rr < 4; rr++)
    *(float4*)&wbuf[wid][rr*256 + lane*4] = bacc[rr];
  __syncthreads();
  #pragma unroll
  for (int q = 0; q < 4; q++) {
    int o = t + q*256;
    int rr = o >> 8, jc = o & 255;
    float s = wbuf[0][o] + wbuf[1][o] + wbuf[2][o] + wbuf[3][o];
    atomicAdd(&bwd[(size_t)b*2048 + (size_t)(jh*256 + jc)*4 + rr], s);
  }
}

// ======================= lookup softmax + Wr_n + read_v + y =======================
__global__ __launch_bounds__(1024) void k_final(const float* __restrict__ fwd,
    const float* __restrict__ bwd, const float* __restrict__ sims,
    const float* __restrict__ params, const float* __restrict__ Wro,
    float* __restrict__ out)
{
  __shared__ float wrl[2048];
  __shared__ float buf[1024];
  __shared__ float rv[256];
  __shared__ float mo[12];
  __shared__ float4 redm[8], reds[8];
  int b = blockIdx.x, t = threadIdx.x;
  int lane = t & 63, wid = t >> 6;
  const float* pp = params + b*512;
  if (t < 12) mo[t] = pp[PK_MOD + t];

  float4 s4 = make_float4(0.f,0.f,0.f,0.f);
  if (t < 512) {
    s4 = *(const float4*)&sims[(size_t)(b*512+t)*4];
    float4 m4 = s4;
    #pragma unroll
    for (int off = 32; off > 0; off >>= 1) {
      m4.x = fmaxf(m4.x, __shfl_xor(m4.x, off));
      m4.y = fmaxf(m4.y, __shfl_xor(m4.y, off));
      m4.z = fmaxf(m4.z, __shfl_xor(m4.z, off));
      m4.w = fmaxf(m4.w, __shfl_xor(m4.w, off));
    }
    if (lane == 0) redm[wid] = m4;
  }
  __syncthreads();
  float4 e4 = make_float4(0.f,0.f,0.f,0.f);
  if (t < 512) {
    float4 mx = redm[0];
    #pragma unroll
    for (int i = 1; i < 8; i++) {
      mx.x = fmaxf(mx.x, redm[i].x); mx.y = fmaxf(mx.y, redm[i].y);
      mx.z = fmaxf(mx.z, redm[i].z); mx.w = fmaxf(mx.w, redm[i].w);
    }
    e4.x = expf(s4.x - mx.x); e4.y = expf(s4.y - mx.y);
    e4.z = expf(s4.z - mx.z); e4.w = expf(s4.w - mx.w);
    float4 t4 = e4;
    #pragma unroll
    for (int off = 32; off > 0; off >>= 1) {
      t4.x += __shfl_xor(t4.x, off); t4.y += __shfl_xor(t4.y, off);
      t4.z += __shfl_xor(t4.z, off); t4.w += __shfl_xor(t4.w, off);
    }
    if (lane == 0) reds[wid] = t4;
  }
  __syncthreads();
  if (t < 512) {
    float4 dn = reds[0];
    #pragma unroll
    for (int i = 1; i < 8; i++) { dn.x += reds[i].x; dn.y += reds[i].y; dn.z += reds[i].z; dn.w += reds[i].w; }
    float4 lk; lk.x = e4.x/dn.x; lk.y = e4.y/dn.y; lk.z = e4.z/dn.z; lk.w = e4.w/dn.w;
    size_t o = (size_t)(b*512 + t)*4;
    float4 f4 = *(const float4*)&fwd[o];
    float4 b4 = *(const float4*)&bwd[o];
    float4 w;
    w.x = mo[0]*b4.x + mo[4]*lk.x + mo[8] *f4.x;
    w.y = mo[1]*b4.y + mo[5]*lk.y + mo[9] *f4.y;
    w.z = mo[2]*b4.z + mo[6]*lk.z + mo[10]*f4.z;
    w.w = mo[3]*b4.w + mo[7]*lk.w + mo[11]*f4.w;
    *(float4*)&out[O_WRN + o] = w;
    *(float4*)&wrl[t*4] = w;
  }
  __syncthreads();

  {
    int w = lane, r = wid & 3, n4 = t >> 8;
    const float* mnb = out + O_MN + (size_t)b*32768 + w;
    float acc = 0.f;
    int nb = n4*128;
    #pragma unroll 4
    for (int n = nb; n < nb + 128; n++) acc += wrl[n*4 + r] * mnb[(size_t)n*64];
    buf[t] = acc;
  }
  __syncthreads();
  if (t < 256) rv[t] = buf[t] + buf[t+256] + buf[t+512] + buf[t+768];
  __syncthreads();

  {
    int o = t & 255, k4 = t >> 8;
    float acc = 0.f;
    #pragma unroll 4
    for (int k = k4*64; k < k4*64 + 64; k++) acc += rv[k] * Wro[k*256 + o];
    buf[t] = acc;
  }
  __syncthreads();
  if (t < 256) out[O_Y + b*256 + t] = buf[t] + buf[t+256] + buf[t+512] + buf[t+768];
}

// ======================= launch =======================
extern "C" void kernel_launch(void* const* d_in, const int* in_sizes, int n_in,
                              void* d_out, int out_size, void* d_ws, size_t ws_size,
                              hipStream_t stream)
{
  const float* inputs  = (const float*)d_in[0];
  const float* M       = (const float*)d_in[1];
  const float* usage   = (const float*)d_in[2];
  const float* L       = (const float*)d_in[3];
  const float* Wp      = (const float*)d_in[4];
  const float* W_read  = (const float*)d_in[5];
  const float* W_write = (const float*)d_in[6];
  const float* h_ctrl  = (const float*)d_in[7];
  const float* W_iface = (const float*)d_in[8];
  const float* W_ro    = (const float*)d_in[9];
  const float* gk      = (const float*)d_in[10];
  const float* grk     = (const float*)d_in[11];
  const float* gb      = (const float*)d_in[12];
  float* out = (float*)d_out;
  float* ws  = (float*)d_ws;

  k_gemm1<<<dim3(35,16), 256, 0, stream>>>(inputs, h_ctrl, gk, grk, ws + WS_P1);
  k_gru<<<(128*CDIM_ + 255)/256, 256, 0, stream>>>(ws + WS_P1, h_ctrl, gb, ws + WS_C, out + O_HC);
  k_gemm2<<<dim3(8,12), 256, 0, stream>>>(ws + WS_C, W_iface, ws + WS_P2);
  k_small<<<64, 512, 0, stream>>>(ws + WS_P2, M, usage, W_read, W_write, Wp, out,
                                  ws + WS_PAR, ws + WS_FWD);
  k_mn<<<2048, 256, 0, stream>>>(M, ws + WS_PAR, out, ws + WS_SIM);
  k_ln<<<1024, 256, 0, stream>>>(L, Wp, W_read, out, ws + WS_FWD, ws + WS_BWD);
  k_final<<<64, 1024, 0, stream>>>(ws + WS_FWD, ws + WS_BWD, ws + WS_SIM, ws + WS_PAR, W_ro, out);
}

// Round 4
// 291.472 us; speedup vs baseline: 1.0313x; 1.0313x over previous
//
#include <hip/hip_runtime.h>
#include <math.h>

#define NN 512
#define WD 64
#define RH 4
#define OUTD 256
#define IND 256
#define IFACE_ 471
#define CDIM_ 727
#define TC 2181   // 3*CDIM
#define BS_ 64

// ---- output offsets (floats) ----
#define O_Y   0
#define O_MN  16384
#define O_UN  2113536
#define O_LN  2146304
#define O_WPN 18923520
#define O_WRN 18956288
#define O_WW  19087360
#define O_HC  19120128

// ---- workspace offsets (floats) ----
// P1: 16 slices x (128x2181) GRU partials. FWD/SIM/BWDP alias P1 (dead after k_gru).
#define P1_STRIDE 279168     // 128*2181
#define WS_P1   0            // 16*279168 = 4466688
#define WS_FWD  0            // 131072   (aliases P1)
#define WS_SIM  131072       // 131072   (aliases P1)
#define WS_BWDP 262144       // 64*8*2048 = 1048576 (aliases P1)
#define WS_P2   4466688      // 12*65536 = 786432
#define P2_STRIDE 65536      // 128*512
#define WS_C    5253120      // 128*727 = 93056
#define WS_PAR  5346176      // 64*512 = 32768  -> end 5378944 floats (21.5 MB)

// ---- per-batch param layout (stride 512) ----
#define PK_NKW 0
#define PK_ER  64
#define PK_WV  128
#define PK_NKR 192
#define PK_BR  448
#define PK_MOD 452
#define PK_BW  464
#define PK_AG  465
#define PK_WG  466
#define PK_FG  468

__device__ __forceinline__ float sigf(float x){ return 1.f/(1.f+expf(-x)); }
__device__ __forceinline__ float softplusf(float x){ return (x>20.f)? x : log1pf(expf(x)); }
__device__ __forceinline__ float geluf(float x){ return 0.5f*x*(1.f+erff(x*0.70710678118654752440f)); }
__device__ __forceinline__ float dot4(float4 a, float4 b){ return a.x*b.x+a.y*b.y+a.z*b.z+a.w*b.w; }
__device__ __forceinline__ void fma4(float4& a, float s, float4 v){ a.x+=s*v.x; a.y+=s*v.y; a.z+=s*v.z; a.w+=s*v.w; }
__device__ __forceinline__ float4 ln_combine(float4 l4, float4 wwj, float4 wpj, float base, float wwi){
  float4 r;
  r.x = (base - wwj.x)*l4.x + wwi*wpj.x;
  r.y = (base - wwj.y)*l4.y + wwi*wpj.y;
  r.z = (base - wwj.z)*l4.z + wwi*wpj.z;
  r.w = (base - wwj.w)*l4.w + wwi*wpj.w;
  return r;
}
__device__ __forceinline__ void diag_zero(float4& r, int d){
  if (d==0) r.x=0.f; else if (d==1) r.y=0.f; else if (d==2) r.z=0.f; else if (d==3) r.w=0.f;
}

// ======================= broadcast GEMM: 64 rows x 64 cols x K-slice =======================
__device__ __forceinline__ void gemm_bc64(
    const float* __restrict__ A, int lda, int K,
    const float* __restrict__ B, int ldb, int Ncols,
    float* __restrict__ C, int ldc,
    int k0, int klen, int n0, int t, float* As)
{
  for (int i = t; i < 4096; i += 256) {
    int m = i >> 6, kk = i & 63;
    As[i] = (kk < klen) ? A[m*lda + k0 + kk] : 0.f;
  }
  int c = n0 + (t & 63);
  int cc = (c < Ncols) ? c : 0;
  int m0 = (t >> 6) * 16;
  float acc[16];
  #pragma unroll
  for (int r = 0; r < 16; r++) acc[r] = 0.f;
  __syncthreads();
  const float* Bc = B + cc;
  for (int kk = 0; kk < 64; kk += 4) {
    int r0 = k0 + kk;
    int i0 = min(r0+0, K-1), i1 = min(r0+1, K-1), i2 = min(r0+2, K-1), i3 = min(r0+3, K-1);
    float b0 = Bc[(size_t)i0*ldb];
    float b1 = Bc[(size_t)i1*ldb];
    float b2 = Bc[(size_t)i2*ldb];
    float b3 = Bc[(size_t)i3*ldb];
    const float* ap = As + kk;
    #pragma unroll
    for (int r = 0; r < 16; r++) {
      float4 a4 = *(const float4*)&ap[(m0+r)*64];
      acc[r] += a4.x*b0 + a4.y*b1 + a4.z*b2 + a4.w*b3;
    }
  }
  if (c < Ncols) {
    float* Cp = C + c;
    #pragma unroll
    for (int r = 0; r < 16; r++) Cp[(size_t)(m0+r)*ldc] = acc[r];
  }
}

// grid (35, 16, 2): x = n-tile of 64 over 2181, y = K-slice (0-3: x-GEMM, 4-15: h-GEMM), z = row half
__global__ __launch_bounds__(256) void k_gemm1(const float* __restrict__ xin,
    const float* __restrict__ hin, const float* __restrict__ gk,
    const float* __restrict__ grk, float* __restrict__ P)
{
  __shared__ float As[4096];
  int s = blockIdx.y, rh = blockIdx.z;
  int n0 = blockIdx.x * 64;
  const float* A; const float* B; int lda, K, k0, klen;
  if (s < 4) { A = xin + rh*64*IND;   lda = IND;   B = gk;  K = IND;   k0 = s*64;      klen = 64; }
  else       { A = hin + rh*64*CDIM_; lda = CDIM_; B = grk; K = CDIM_; k0 = (s-4)*61;  klen = (s==15)?56:61; }
  gemm_bc64(A, lda, K, B, TC, TC,
            P + (size_t)s*P1_STRIDE + (size_t)rh*64*TC, TC,
            k0, klen, n0, threadIdx.x, As);
}

// grid (8, 12, 2)
__global__ __launch_bounds__(256) void k_gemm2(const float* __restrict__ cbuf,
    const float* __restrict__ Wif, float* __restrict__ P2)
{
  __shared__ float As[4096];
  int s = blockIdx.y, rh = blockIdx.z;
  int k0 = s*61, klen = (s==11)?56:61;
  gemm_bc64(cbuf + rh*64*CDIM_, CDIM_, CDIM_, Wif, IFACE_, IFACE_,
            P2 + (size_t)s*P2_STRIDE + (size_t)rh*64*512, 512,
            k0, klen, blockIdx.x*64, threadIdx.x, As);
}

// ======================= GRU pointwise =======================
__global__ __launch_bounds__(256) void k_gru(const float* __restrict__ P,
    const float* __restrict__ hprev, const float* __restrict__ gbias,
    float* __restrict__ cbuf, float* __restrict__ out_hc)
{
  int idx = blockIdx.x*256 + threadIdx.x;
  if (idx >= 128*CDIM_) return;
  int p = idx / CDIM_, u = idx % CDIM_;
  float zs=0.f, rs=0.f, xh=0.f, rh=0.f;
  #pragma unroll
  for (int s = 0; s < 16; s++) {
    const float* Ps = P + (size_t)s*P1_STRIDE + (size_t)p*TC;
    zs += Ps[u]; rs += Ps[CDIM_+u];
    float hv = Ps[2*CDIM_+u];
    if (s < 4) xh += hv; else rh += hv;
  }
  zs += gbias[u] + gbias[TC+u];
  rs += gbias[CDIM_+u] + gbias[TC+CDIM_+u];
  xh += gbias[2*CDIM_+u];
  rh += gbias[TC+2*CDIM_+u];
  float z_ = sigf(zs);
  float r_ = sigf(rs);
  float hh = geluf(xh + r_*rh);
  float h  = hprev[(size_t)p*CDIM_ + u];
  float cv = z_*h + (1.f - z_)*hh;
  cbuf[(size_t)p*CDIM_ + u] = cv;
  out_hc[(size_t)p*CDIM_ + u] = cv;
}

// ======================= per-batch small ops =======================
__global__ __launch_bounds__(512) void k_small(
    const float* __restrict__ P2, const float* __restrict__ M,
    const float* __restrict__ usage, const float* __restrict__ W_read,
    const float* __restrict__ W_write, const float* __restrict__ Wp,
    float* __restrict__ out, float* __restrict__ params)
{
  __shared__ float ifr[IFACE_], ifw[IFACE_];
  __shared__ float su[512]; __shared__ int si[512];
  __shared__ float alloc_l[512];
  __shared__ float s_nkw[64];
  __shared__ float s_fg[4];
  __shared__ float s_bw, s_ag, s_wg;
  __shared__ float wredA[8], wredB[8], warpTot[8];
  int b = blockIdx.x, t = threadIdx.x;
  int lane = t & 63, wid = t >> 6;
  float* pp = params + b*512;

  if (t < IFACE_) {
    float sr = 0.f, sw = 0.f;
    #pragma unroll
    for (int s = 0; s < 12; s++) {
      const float* base = P2 + (size_t)s*P2_STRIDE;
      sr += base[(b*2+0)*512 + t];
      sw += base[(b*2+1)*512 + t];
    }
    ifr[t] = sr; ifw[t] = sw;
  }
  __syncthreads();

  if (t < 64) {
    float ss = 0.f;
    for (int w = 0; w < 64; w++) { float v = ifw[260+w]; ss += v*v; }
    float rn = rsqrtf(fmaxf(ss, 1e-12f));
    float nk = ifw[260+t]*rn;
    pp[PK_NKW + t] = nk; s_nkw[t] = nk;
    pp[PK_ER  + t] = sigf(ifw[325+t]);
    pp[PK_WV  + t] = ifw[389+t];
  } else if (t < 320) {
    int r = (t-64) >> 6, w = (t-64) & 63;
    float ss = 0.f;
    for (int w2 = 0; w2 < 64; w2++) { float v = ifr[r*64+w2]; ss += v*v; }
    pp[PK_NKR + r*64 + w] = ifr[r*64+w]*rsqrtf(fmaxf(ss, 1e-12f));
  } else if (t < 324) {
    pp[PK_BR + (t-320)] = 1.f + softplusf(ifr[256 + (t-320)]);
  } else if (t < 336) {
    int i = t-324; int mm = i >> 2, r = i & 3;
    float v0 = ifr[459+r], v1 = ifr[459+4+r], v2 = ifr[459+8+r];
    float mx = fmaxf(v0, fmaxf(v1, v2));
    float e0 = expf(v0-mx), e1 = expf(v1-mx), e2 = expf(v2-mx);
    float den = e0+e1+e2;
    pp[PK_MOD + i] = (mm==0 ? e0 : (mm==1 ? e1 : e2)) / den;
  } else if (t == 336) { float v = 1.f + softplusf(ifw[324]); pp[PK_BW] = v; s_bw = v; }
  else if (t == 337) { float v = sigf(ifw[457]); pp[PK_AG] = v; s_ag = v; }
  else if (t == 338) { float v = sigf(ifw[458]); pp[PK_WG] = v; s_wg = v; }
  else if (t < 343) { int r = t-339; float v = sigf(ifw[453+r]); pp[PK_FG+r] = v; s_fg[r] = v; }
  __syncthreads();

  float un;
  {
    float4 wr4 = *(const float4*)&W_read[(size_t)(b*512+t)*4];
    float ret = (1.f - s_fg[0]*wr4.x)*(1.f - s_fg[1]*wr4.y)*(1.f - s_fg[2]*wr4.z)*(1.f - s_fg[3]*wr4.w);
    float u = usage[b*512+t], w = W_write[b*512+t];
    un = (u + w - u*w)*ret;
    out[O_UN + b*512 + t] = un;
  }

  float v = un; int key = t;
  for (int k = 2; k <= 512; k <<= 1) {
    for (int j = k >> 1; j > 0; j >>= 1) {
      bool dir = ((t & k) == 0);
      if (j >= 64) {
        su[t] = v; si[t] = key;
        __syncthreads();
        float pv = su[t ^ j]; int pi = si[t ^ j];
        bool gt = (v > pv) || (v == pv && key > pi);
        bool take = ((t & j) == 0) ? (gt == dir) : (gt != dir);
        if (take) { v = pv; key = pi; }
        __syncthreads();
      } else {
        float pv = __shfl_xor(v, j);
        int   pi = __shfl_xor(key, j);
        bool gt = (v > pv) || (v == pv && key > pi);
        bool take = ((t & j) == 0) ? (gt == dir) : (gt != dir);
        if (take) { v = pv; key = pi; }
      }
    }
  }

  {
    float x = v;
    #pragma unroll
    for (int off = 1; off < 64; off <<= 1) {
      float y = __shfl_up(x, off);
      if (lane >= off) x *= y;
    }
    if (lane == 63) warpTot[wid] = x;
    __syncthreads();
    float pre = 1.f;
    for (int w2 = 0; w2 < wid; w2++) pre *= warpTot[w2];
    float xm1 = __shfl_up(x, 1);
    float excl = (lane == 0) ? pre : pre*xm1;
    alloc_l[key] = (1.f - v)*excl;
  }
  __syncthreads();

  float mysim;
  {
    const float* mrow = M + (size_t)(b*512+t)*64;
    float ss = 0.f, dt = 0.f;
    #pragma unroll
    for (int i = 0; i < 16; i++) {
      float4 m4 = *(const float4*)&mrow[i*4];
      float4 k4 = *(const float4*)&s_nkw[i*4];
      ss += dot4(m4, m4); dt += dot4(m4, k4);
    }
    mysim = dt * rsqrtf(fmaxf(ss, 1e-12f)) * s_bw;
  }
  float mw = mysim;
  #pragma unroll
  for (int off = 32; off > 0; off >>= 1) mw = fmaxf(mw, __shfl_xor(mw, off));
  if (lane == 0) wredA[wid] = mw;
  __syncthreads();
  float mx = wredA[0];
  #pragma unroll
  for (int i = 1; i < 8; i++) mx = fmaxf(mx, wredA[i]);
  float e = expf(mysim - mx);
  float sw_ = e;
  #pragma unroll
  for (int off = 32; off > 0; off >>= 1) sw_ += __shfl_xor(sw_, off);
  if (lane == 0) wredB[wid] = sw_;
  __syncthreads();
  float den = 0.f;
  #pragma unroll
  for (int i = 0; i < 8; i++) den += wredB[i];
  float lkp = e / den;

  float ww = s_wg * (s_ag * alloc_l[t] + (1.f - s_ag) * lkp);
  out[O_WW + b*512 + t] = ww;
  float wsum = ww;
  #pragma unroll
  for (int off = 32; off > 0; off >>= 1) wsum += __shfl_xor(wsum, off);
  if (lane == 0) wredA[wid] = wsum;
  __syncthreads();
  float sum = 0.f;
  #pragma unroll
  for (int i = 0; i < 8; i++) sum += wredA[i];

  out[O_WPN + b*512 + t] = (1.f - sum)*Wp[b*512+t] + ww;
}

// ======================= L_n + W_fwd + W_bwd + M_n + sims (fused) =======================
// grid: 512 = (b, it of 64 rows). Block covers full 512 cols per row; no global atomics.
__global__ __launch_bounds__(256) void k_ln(const float* __restrict__ L,
    const float* __restrict__ Wp, const float* __restrict__ W_read,
    const float* __restrict__ M, const float* __restrict__ params,
    float* __restrict__ out, float* __restrict__ fwd,
    float* __restrict__ bwdp, float* __restrict__ sims)
{
  __shared__ float wwl[512], wpl[512];
  __shared__ float wrT[4][512];
  __shared__ float bwdl[2048];       // [rr*512 + j]
  __shared__ float sER[64], sWV[64], sNKR[256], sBR[4];
  int bid = blockIdx.x;
  int b  = bid >> 3;
  int it = bid & 7;
  int i0 = it * 64;
  int t = threadIdx.x, lane = t & 63, wid = t >> 6;
  const float* pp = params + b*512;

  for (int q = 0; q < 2; q++) {
    int n = t + q*256;
    wwl[n] = out[O_WW + b*512 + n];
    wpl[n] = Wp[b*512 + n];
    float4 w4 = *(const float4*)&W_read[(size_t)(b*512+n)*4];
    wrT[0][n] = w4.x; wrT[1][n] = w4.y; wrT[2][n] = w4.z; wrT[3][n] = w4.w;
  }
  #pragma unroll
  for (int q = 0; q < 8; q++) bwdl[t + q*256] = 0.f;
  if (t < 64)       sER[t]      = pp[PK_ER + t];
  else if (t < 128) sWV[t-64]   = pp[PK_WV + (t-64)];
  else if (t < 132) sBR[t-128]  = pp[PK_BR + (t-128)];
  if (t < 256) sNKR[t] = pp[PK_NKR + t];
  __syncthreads();

  // ---- fused M_n + sims for rows i0..i0+63 (1/4 row per thread) ----
  {
    int mrow = t >> 2, mq = t & 3;
    int gr = i0 + mrow;
    float ww = wwl[gr];
    const float* Mr = M + (size_t)(b*512+gr)*64 + mq*16;
    float* MNr = out + O_MN + (size_t)(b*512+gr)*64 + mq*16;
    float ss=0.f, d0=0.f, d1=0.f, d2=0.f, d3=0.f;
    #pragma unroll
    for (int i = 0; i < 4; i++) {
      int c = mq*16 + i*4;
      float4 m4 = *(const float4*)&Mr[i*4];
      float4 er = *(const float4*)&sER[c];
      float4 wv = *(const float4*)&sWV[c];
      float4 r;
      r.x = m4.x*(1.f - ww*er.x) + ww*wv.x;
      r.y = m4.y*(1.f - ww*er.y) + ww*wv.y;
      r.z = m4.z*(1.f - ww*er.z) + ww*wv.z;
      r.w = m4.w*(1.f - ww*er.w) + ww*wv.w;
      *(float4*)&MNr[i*4] = r;
      ss += dot4(r, r);
      d0 += dot4(r, *(const float4*)&sNKR[      c]);
      d1 += dot4(r, *(const float4*)&sNKR[ 64 + c]);
      d2 += dot4(r, *(const float4*)&sNKR[128 + c]);
      d3 += dot4(r, *(const float4*)&sNKR[192 + c]);
    }
    #pragma unroll
    for (int m = 1; m < 4; m <<= 1) {
      ss += __shfl_xor(ss, m);
      d0 += __shfl_xor(d0, m); d1 += __shfl_xor(d1, m);
      d2 += __shfl_xor(d2, m); d3 += __shfl_xor(d3, m);
    }
    if (mq == 0) {
      float rn = rsqrtf(fmaxf(ss, 1e-12f));
      float4 s;
      s.x = d0*rn*sBR[0]; s.y = d1*rn*sBR[1];
      s.z = d2*rn*sBR[2]; s.w = d3*rn*sBR[3];
      *(float4*)&sims[(size_t)(b*512+gr)*4] = s;
    }
  }

  // ---- main L loop: wave handles 16 rows, full 512 cols each ----
  int jb0 = lane*4, jb1 = 256 + lane*4;
  float4 ww0 = *(const float4*)&wwl[jb0], ww1 = *(const float4*)&wwl[jb1];
  float4 wp0 = *(const float4*)&wpl[jb0], wp1 = *(const float4*)&wpl[jb1];
  float4 wr0[4], wr1[4], b0[4], b1[4];
  #pragma unroll
  for (int rr = 0; rr < 4; rr++) {
    wr0[rr] = *(const float4*)&wrT[rr][jb0];
    wr1[rr] = *(const float4*)&wrT[rr][jb1];
    b0[rr] = make_float4(0.f,0.f,0.f,0.f);
    b1[rr] = make_float4(0.f,0.f,0.f,0.f);
  }
  const float* Lb  = L + (size_t)b*262144;
  float* LNb = out + O_LN + (size_t)b*262144;
  #pragma unroll 2
  for (int ri = 0; ri < 16; ri++) {
    int gi = i0 + wid*16 + ri;
    float wwi = wwl[gi], base = 1.f - wwi;
    float wi0 = wrT[0][gi], wi1 = wrT[1][gi], wi2 = wrT[2][gi], wi3 = wrT[3][gi];
    const float* lrow = Lb + (size_t)gi*512;
    float* orow = LNb + (size_t)gi*512;
    float4 l0 = *(const float4*)&lrow[jb0];
    float4 l1 = *(const float4*)&lrow[jb1];
    float4 r0 = ln_combine(l0, ww0, wp0, base, wwi);
    diag_zero(r0, gi - jb0);
    float4 r1 = ln_combine(l1, ww1, wp1, base, wwi);
    diag_zero(r1, gi - jb1);
    *(float4*)&orow[jb0] = r0;
    *(float4*)&orow[jb1] = r1;
    float f0 = dot4(r0, wr0[0]) + dot4(r1, wr1[0]);
    float f1 = dot4(r0, wr0[1]) + dot4(r1, wr1[1]);
    float f2 = dot4(r0, wr0[2]) + dot4(r1, wr1[2]);
    float f3 = dot4(r0, wr0[3]) + dot4(r1, wr1[3]);
    fma4(b0[0], wi0, r0); fma4(b0[1], wi1, r0); fma4(b0[2], wi2, r0); fma4(b0[3], wi3, r0);
    fma4(b1[0], wi0, r1); fma4(b1[1], wi1, r1); fma4(b1[2], wi2, r1); fma4(b1[3], wi3, r1);
    // quad-pack: lane m (mod 4) ends with f_m quad-sum, then butterfly
    float s1 = (lane & 1) ? f0 : f1;
    float p  = ((lane & 1) ? f1 : f0) + __shfl_xor(s1, 1);
    float s2 = (lane & 1) ? f2 : f3;
    float q  = ((lane & 1) ? f3 : f2) + __shfl_xor(s2, 1);
    float s3 = (lane & 2) ? p : q;
    float w  = ((lane & 2) ? q : p) + __shfl_xor(s3, 2);
    #pragma unroll
    for (int off = 4; off < 64; off <<= 1) w += __shfl_xor(w, off);
    if (lane < 4) fwd[(size_t)(b*512+gi)*4 + lane] = w;
  }
  // bwd: LDS atomic accumulate (block scope), then plain store to per-tile slot
  #pragma unroll
  for (int rr = 0; rr < 4; rr++) {
    atomicAdd(&bwdl[rr*512 + jb0+0], b0[rr].x);
    atomicAdd(&bwdl[rr*512 + jb0+1], b0[rr].y);
    atomicAdd(&bwdl[rr*512 + jb0+2], b0[rr].z);
    atomicAdd(&bwdl[rr*512 + jb0+3], b0[rr].w);
    atomicAdd(&bwdl[rr*512 + jb1+0], b1[rr].x);
    atomicAdd(&bwdl[rr*512 + jb1+1], b1[rr].y);
    atomicAdd(&bwdl[rr*512 + jb1+2], b1[rr].z);
    atomicAdd(&bwdl[rr*512 + jb1+3], b1[rr].w);
  }
  __syncthreads();
  float* slot = bwdp + (size_t)(b*8 + it)*2048;
  #pragma unroll
  for (int q2 = 0; q2 < 8; q2++) {
    int o = t + q2*256;             // flat j*4+rr
    int j = o >> 2, rr = o & 3;
    slot[o] = bwdl[rr*512 + j];
  }
}

// ======================= lookup softmax + Wr_n + read_v + y =======================
__global__ __launch_bounds__(1024) void k_final(const float* __restrict__ fwd,
    const float* __restrict__ bwdp, const float* __restrict__ sims,
    const float* __restrict__ params, const float* __restrict__ Wro,
    float* __restrict__ out)
{
  __shared__ float wrl[2048];
  __shared__ float buf[1024];
  __shared__ float rv[256];
  __shared__ float mo[12];
  __shared__ float4 redm[8], reds[8];
  int b = blockIdx.x, t = threadIdx.x;
  int lane = t & 63, wid = t >> 6;
  const float* pp = params + b*512;
  if (t < 12) mo[t] = pp[PK_MOD + t];

  float4 s4 = make_float4(0.f,0.f,0.f,0.f);
  if (t < 512) {
    s4 = *(const float4*)&sims[(size_t)(b*512+t)*4];
    float4 m4 = s4;
    #pragma unroll
    for (int off = 32; off > 0; off >>= 1) {
      m4.x = fmaxf(m4.x, __shfl_xor(m4.x, off));
      m4.y = fmaxf(m4.y, __shfl_xor(m4.y, off));
      m4.z = fmaxf(m4.z, __shfl_xor(m4.z, off));
      m4.w = fmaxf(m4.w, __shfl_xor(m4.w, off));
    }
    if (lane == 0) redm[wid] = m4;
  }
  __syncthreads();
  float4 e4 = make_float4(0.f,0.f,0.f,0.f);
  if (t < 512) {
    float4 mx = redm[0];
    #pragma unroll
    for (int i = 1; i < 8; i++) {
      mx.x = fmaxf(mx.x, redm[i].x); mx.y = fmaxf(mx.y, redm[i].y);
      mx.z = fmaxf(mx.z, redm[i].z); mx.w = fmaxf(mx.w, redm[i].w);
    }
    e4.x = expf(s4.x - mx.x); e4.y = expf(s4.y - mx.y);
    e4.z = expf(s4.z - mx.z); e4.w = expf(s4.w - mx.w);
    float4 t4 = e4;
    #pragma unroll
    for (int off = 32; off > 0; off >>= 1) {
      t4.x += __shfl_xor(t4.x, off); t4.y += __shfl_xor(t4.y, off);
      t4.z += __shfl_xor(t4.z, off); t4.w += __shfl_xor(t4.w, off);
    }
    if (lane == 0) reds[wid] = t4;
  }
  __syncthreads();
  if (t < 512) {
    float4 dn = reds[0];
    #pragma unroll
    for (int i = 1; i < 8; i++) { dn.x += reds[i].x; dn.y += reds[i].y; dn.z += reds[i].z; dn.w += reds[i].w; }
    float4 lk; lk.x = e4.x/dn.x; lk.y = e4.y/dn.y; lk.z = e4.z/dn.z; lk.w = e4.w/dn.w;
    size_t o = (size_t)(b*512 + t)*4;
    float4 f4 = *(const float4*)&fwd[o];
    float4 b4 = make_float4(0.f,0.f,0.f,0.f);
    #pragma unroll
    for (int it = 0; it < 8; it++) {
      float4 p4 = *(const float4*)&bwdp[(size_t)(b*8+it)*2048 + t*4];
      b4.x += p4.x; b4.y += p4.y; b4.z += p4.z; b4.w += p4.w;
    }
    float4 w;
    w.x = mo[0]*b4.x + mo[4]*lk.x + mo[8] *f4.x;
    w.y = mo[1]*b4.y + mo[5]*lk.y + mo[9] *f4.y;
    w.z = mo[2]*b4.z + mo[6]*lk.z + mo[10]*f4.z;
    w.w = mo[3]*b4.w + mo[7]*lk.w + mo[11]*f4.w;
    *(float4*)&out[O_WRN + o] = w;
    *(float4*)&wrl[t*4] = w;
  }
  __syncthreads();

  {
    int w = lane, r = wid & 3, n4 = t >> 8;
    const float* mnb = out + O_MN + (size_t)b*32768 + w;
    float acc = 0.f;
    int nb = n4*128;
    #pragma unroll 4
    for (int n = nb; n < nb + 128; n++) acc += wrl[n*4 + r] * mnb[(size_t)n*64];
    buf[t] = acc;
  }
  __syncthreads();
  if (t < 256) rv[t] = buf[t] + buf[t+256] + buf[t+512] + buf[t+768];
  __syncthreads();

  {
    int o = t & 255, k4 = t >> 8;
    float acc = 0.f;
    #pragma unroll 4
    for (int k = k4*64; k < k4*64 + 64; k++) acc += rv[k] * Wro[k*256 + o];
    buf[t] = acc;
  }
  __syncthreads();
  if (t < 256) out[O_Y + b*256 + t] = buf[t] + buf[t+256] + buf[t+512] + buf[t+768];
}

// ======================= launch =======================
extern "C" void kernel_launch(void* const* d_in, const int* in_sizes, int n_in,
                              void* d_out, int out_size, void* d_ws, size_t ws_size,
                              hipStream_t stream)
{
  const float* inputs  = (const float*)d_in[0];
  const float* M       = (const float*)d_in[1];
  const float* usage   = (const float*)d_in[2];
  const float* L       = (const float*)d_in[3];
  const float* Wp      = (const float*)d_in[4];
  const float* W_read  = (const float*)d_in[5];
  const float* W_write = (const float*)d_in[6];
  const float* h_ctrl  = (const float*)d_in[7];
  const float* W_iface = (const float*)d_in[8];
  const float* W_ro    = (const float*)d_in[9];
  const float* gk      = (const float*)d_in[10];
  const float* grk     = (const float*)d_in[11];
  const float* gb      = (const float*)d_in[12];
  float* out = (float*)d_out;
  float* ws  = (float*)d_ws;

  k_gemm1<<<dim3(35,16,2), 256, 0, stream>>>(inputs, h_ctrl, gk, grk, ws + WS_P1);
  k_gru<<<(128*CDIM_ + 255)/256, 256, 0, stream>>>(ws + WS_P1, h_ctrl, gb, ws + WS_C, out + O_HC);
  k_gemm2<<<dim3(8,12,2), 256, 0, stream>>>(ws + WS_C, W_iface, ws + WS_P2);
  k_small<<<64, 512, 0, stream>>>(ws + WS_P2, M, usage, W_read, W_write, Wp, out, ws + WS_PAR);
  k_ln<<<512, 256, 0, stream>>>(L, Wp, W_read, M, ws + WS_PAR, out,
                                ws + WS_FWD, ws + WS_BWDP, ws + WS_SIM);
  k_final<<<64, 1024, 0, stream>>>(ws + WS_FWD, ws + WS_BWDP, ws + WS_SIM,
                                   ws + WS_PAR, W_ro, out);
}